// Round 6
// baseline (459.437 us; speedup 1.0000x reference)
//
#include <hip/hip_runtime.h>
#include <math.h>

#define DIM  64
#define HID  128
#define KNN  16
#define SEG  1024   // candidates per wave-segment (NPB/4)
#define TSZ  128    // position tile size per segment
#define CAP  12     // per-thread LDS candidate buffer capacity

typedef unsigned long long u64;
#define INF_BITS 0x7F800000u

// Insert (d,g) into ascending-sorted (bd,bi), dropping old max.
// Strict < on value + index-ascending processing order reproduces top_k's
// stable (d, idx) lex rule exactly (incumbent always has smaller index).
__device__ __forceinline__ void ins16(float (&bd)[KNN], int (&bi)[KNN],
                                      float d, int g) {
    float cd = d; int ci = g;
    #pragma unroll
    for (int i = 0; i < KNN; ++i) {
        bool lt = cd < bd[i];
        float dl = lt ? cd : bd[i];
        float dh = lt ? bd[i] : cd;
        int   il = lt ? ci : bi[i];
        int   ih = lt ? bi[i] : ci;
        bd[i] = dl; bi[i] = il; cd = dh; ci = ih;
    }
}

__device__ __forceinline__ void drain_buf(const u64* bufe, int tid,
        float (&bd)[KNN], int (&bi)[KNN], int& cnt,
        unsigned* thrU, int l) {
    for (int t = 0; t < CAP; ++t) {
        if (__ballot(t < cnt) == 0ull) break;
        u64 e = bufe[t * 256 + tid];
        float d = __uint_as_float((unsigned)e);
        int   g = (int)(e >> 32);
        if ((t < cnt) && (d < bd[KNN - 1])) ins16(bd, bi, d, g);
    }
    cnt = 0;
    // publish tightened per-query threshold (uint order == float order, d2>=0)
    atomicMin(&thrU[l], __float_as_uint(bd[KNN - 1]));
}

// float2 helpers, contraction OFF (bit-match numpy's mul/add sequence).
struct f2 { float a, b; };
__device__ __forceinline__ f2 f2mul(f2 x, float s) {
    #pragma clang fp contract(off)
    f2 r; r.a = x.a * s; r.b = x.b * s; return r;
}
__device__ __forceinline__ f2 f2add(f2 x, f2 y) {
    #pragma clang fp contract(off)
    f2 r; r.a = x.a + y.a; r.b = x.b + y.b; return r;
}
__device__ __forceinline__ f2 f2adds(f2 x, float s) {
    #pragma clang fp contract(off)
    f2 r; r.a = s + x.a; r.b = s + x.b; return r;
}
__device__ __forceinline__ f2 f2sub(f2 x, f2 y) {
    #pragma clang fp contract(off)
    f2 r; r.a = x.a - y.a; r.b = x.b - y.b; return r;
}
__device__ __forceinline__ f2 d2pair(f2 Px, f2 Py, f2 Pz, f2 Ps,
                                     float qx, float qy, float qz, float qs) {
    f2 dot = f2add(f2add(f2mul(Px, qx), f2mul(Py, qy)), f2mul(Pz, qz));
    return f2sub(f2adds(Ps, qs), f2mul(dot, 2.0f));
}

// Per-wave segment scan with cross-wave shared threshold.
// Fast path: one ballot-branch per 8 candidates on min8 <= thr.
template<bool CHECK>
__device__ __forceinline__ void knn_scan(
    const float* __restrict__ pos, int bbase, int segbase, int qlocal, int l,
    float qx, float qy, float qz, float qs,
    float* tx, float* ty, float* tz, float* ts,
    u64* bufe, unsigned* thrU, volatile unsigned* thrv, int tid,
    float (&bd)[KNN], int (&bi)[KNN])
{
    #pragma clang fp contract(off)
    int cnt = 0;

    // tile 0 (wave-private region; in-wave DS ordering suffices)
    #pragma unroll
    for (int m = 0; m < 2; ++m) {
        int t = (m << 6) + l;
        int g = (bbase + segbase + t) * 3;
        float ax = pos[g], ay = pos[g + 1], az = pos[g + 2];
        tx[t] = ax; ty[t] = ay; tz[t] = az;
        ts[t] = (ax * ax + ay * ay) + az * az;
    }

    __syncthreads();   // thr[] init (by wave 0) visible to all waves

    // seed: first 16 candidates of own segment straight into the sorted set
    #pragma unroll
    for (int k = 0; k < KNN; ++k) { bd[k] = INFINITY; bi[k] = 0x7FFFFFFF; }
    for (int jj = 0; jj < KNN; ++jj) {
        float ax = tx[jj], ay = ty[jj], az = tz[jj], as = ts[jj];
        float dot = (ax * qx + ay * qy) + az * qz;
        float d2  = (qs + as) - 2.0f * dot;
        int cj = segbase + jj;
        if (cj == qlocal) d2 = INFINITY;
        ins16(bd, bi, d2, cj);
    }
    atomicMin(&thrU[l], __float_as_uint(bd[KNN - 1]));

    int jstart = KNN;
    for (int tb = 0; tb < SEG; tb += TSZ) {
        if (tb > 0) {
            #pragma unroll
            for (int m = 0; m < 2; ++m) {
                int t = (m << 6) + l;
                int g = (bbase + segbase + tb + t) * 3;
                float ax = pos[g], ay = pos[g + 1], az = pos[g + 2];
                tx[t] = ax; ty[t] = ay; tz[t] = az;
                ts[t] = (ax * ax + ay * ay) + az * az;
            }
        }
        for (int j = jstart; j < TSZ; j += 8) {
            float tl = __uint_as_float(thrv[l]);   // re-read: tightens over time
            float4 X0 = *(const float4*)(tx + j);
            float4 X1 = *(const float4*)(tx + j + 4);
            float4 Y0 = *(const float4*)(ty + j);
            float4 Y1 = *(const float4*)(ty + j + 4);
            float4 Z0 = *(const float4*)(tz + j);
            float4 Z1 = *(const float4*)(tz + j + 4);
            float4 S0 = *(const float4*)(ts + j);
            float4 S1 = *(const float4*)(ts + j + 4);
            const int c0 = segbase + tb + j;

            f2 dA = d2pair({X0.x, X0.y}, {Y0.x, Y0.y}, {Z0.x, Z0.y}, {S0.x, S0.y},
                           qx, qy, qz, qs);
            f2 dB = d2pair({X0.z, X0.w}, {Y0.z, Y0.w}, {Z0.z, Z0.w}, {S0.z, S0.w},
                           qx, qy, qz, qs);
            f2 dC = d2pair({X1.x, X1.y}, {Y1.x, Y1.y}, {Z1.x, Z1.y}, {S1.x, S1.y},
                           qx, qy, qz, qs);
            f2 dD = d2pair({X1.z, X1.w}, {Y1.z, Y1.w}, {Z1.z, Z1.w}, {S1.z, S1.w},
                           qx, qy, qz, qs);
            if (CHECK) {
                int s = qlocal - c0;                  // 0..7 if self in group
                if (s == 0) dA.a = INFINITY;
                if (s == 1) dA.b = INFINITY;
                if (s == 2) dB.a = INFINITY;
                if (s == 3) dB.b = INFINITY;
                if (s == 4) dC.a = INFINITY;
                if (s == 5) dC.b = INFINITY;
                if (s == 6) dD.a = INFINITY;
                if (s == 7) dD.b = INFINITY;
            }
            float mn = fminf(fminf(fminf(dA.a, dA.b), fminf(dB.a, dB.b)),
                             fminf(fminf(dC.a, dC.b), fminf(dD.a, dD.b)));

            if (__ballot(mn <= tl) != 0ull) {
                // slow path: per-candidate test + append (rare after warmup)
                if (dA.a <= tl) {
                    bufe[cnt * 256 + tid] =
                        ((u64)(unsigned)(c0 + 0) << 32) | __float_as_uint(dA.a); ++cnt; }
                if (dA.b <= tl) {
                    bufe[cnt * 256 + tid] =
                        ((u64)(unsigned)(c0 + 1) << 32) | __float_as_uint(dA.b); ++cnt; }
                if (dB.a <= tl) {
                    bufe[cnt * 256 + tid] =
                        ((u64)(unsigned)(c0 + 2) << 32) | __float_as_uint(dB.a); ++cnt; }
                if (dB.b <= tl) {
                    bufe[cnt * 256 + tid] =
                        ((u64)(unsigned)(c0 + 3) << 32) | __float_as_uint(dB.b); ++cnt; }
                if (__ballot(cnt >= CAP - 4) != 0ull)
                    drain_buf(bufe, tid, bd, bi, cnt, thrU, l);
                if (dC.a <= tl) {
                    bufe[cnt * 256 + tid] =
                        ((u64)(unsigned)(c0 + 4) << 32) | __float_as_uint(dC.a); ++cnt; }
                if (dC.b <= tl) {
                    bufe[cnt * 256 + tid] =
                        ((u64)(unsigned)(c0 + 5) << 32) | __float_as_uint(dC.b); ++cnt; }
                if (dD.a <= tl) {
                    bufe[cnt * 256 + tid] =
                        ((u64)(unsigned)(c0 + 6) << 32) | __float_as_uint(dD.a); ++cnt; }
                if (dD.b <= tl) {
                    bufe[cnt * 256 + tid] =
                        ((u64)(unsigned)(c0 + 7) << 32) | __float_as_uint(dD.b); ++cnt; }
                if (__ballot(cnt >= CAP - 4) != 0ull)
                    drain_buf(bufe, tid, bd, bi, cnt, thrU, l);
            }
        }
        jstart = 0;
    }
    drain_buf(bufe, tid, bd, bi, cnt, thrU, l);
}

// Kernel 1: exact 16-NN + gather + aggregate. Writes h = x + sum(nb) to agg_out.
__global__ __launch_bounds__(256, 4) void knn_agg(
    const float* __restrict__ x, const float* __restrict__ pos,
    float* __restrict__ agg_out)
{
    // 32.25 KB LDS. Phase 1: tiles (8 KB) + thr (256 B) + u64 buffers (24 KB).
    // Phase 2 alias: md[64 slots][64 queries] f32 + midx ints (32 KB).
    // Phase 3 alias: mi2[16][64] ints (4 KB).
    __shared__ u64 smem[4128];

    const int tid = threadIdx.x;
    const int w   = tid >> 6;
    const int l   = tid & 63;

    const int qb     = blockIdx.x;          // 1024 blocks x 64 queries
    const int batch  = qb >> 6;
    const int bbase  = batch << 12;
    const int qlocal = ((qb & 63) << 6) + l;
    const int qglob  = bbase + qlocal;

    float* tilef = (float*)smem;            // 2048 floats
    float* tx = tilef + w * 512;
    float* ty = tx + TSZ;
    float* tz = tx + 2 * TSZ;
    float* ts = tx + 3 * TSZ;
    unsigned* thrU = (unsigned*)(tilef + 2048);       // 64 u32
    u64* bufe = smem + 1056;                          // 3072 u64

    if (tid < 64) thrU[tid] = INF_BITS;     // before the barrier inside knn_scan

    float qx, qy, qz, qs;
    {
        #pragma clang fp contract(off)
        qx = pos[3 * qglob + 0];
        qy = pos[3 * qglob + 1];
        qz = pos[3 * qglob + 2];
        qs = (qx * qx + qy * qy) + qz * qz;
    }

    float bd[KNN]; int bi[KNN];
    const int segbase = w << 10;
    const int wself   = (qb & 63) >> 4;
    if (w == wself)
        knn_scan<true >(pos, bbase, segbase, qlocal, l, qx, qy, qz, qs,
                        tx, ty, tz, ts, bufe, thrU, thrU, tid, bd, bi);
    else
        knn_scan<false>(pos, bbase, segbase, qlocal, l, qx, qy, qz, qs,
                        tx, ty, tz, ts, bufe, thrU, thrU, tid, bd, bi);

    __syncthreads();                         // phase-1 LDS dead; re-alias

    // per-wave lists -> md/midx, transposed [slot][query] (conflict-free)
    float* md  = (float*)smem;               // 4096 floats
    int*  midx = (int*)(smem + 2048);        // 4096 ints
    #pragma unroll
    for (int k = 0; k < KNN; ++k) {
        int slot = (w << 4) + k;
        md[slot * 64 + l]   = bd[k];
        midx[slot * 64 + l] = bi[k];
    }
    __syncthreads();

    // merge 4 sorted lists (slot order == index order) -> exact top-16
    if (tid < 64) {
        float bd2[KNN]; int bi2[KNN];
        #pragma unroll
        for (int k = 0; k < KNN; ++k) {      // wave-0 list is already sorted
            bd2[k] = md[k * 64 + tid];
            bi2[k] = midx[k * 64 + tid];
        }
        for (int c = KNN; c < 64; ++c) {
            float d = md[c * 64 + tid];
            int   g = midx[c * 64 + tid];
            if (d < bd2[KNN - 1]) ins16(bd2, bi2, d, g);
        }
        int* mi2 = (int*)smem;               // single-wave: reads above precede writes
        #pragma unroll
        for (int k = 0; k < KNN; ++k) mi2[k * 64 + tid] = bi2[k];
    }
    __syncthreads();

    // gather + aggregate: 4 threads/row, 16 cols each
    {
        const int* mi2 = (const int*)smem;
        const int r  = tid >> 2;
        const int p  = tid & 3;
        const int q  = (qb << 6) + r;
        const int cb = p << 4;

        int idxs[KNN];
        #pragma unroll
        for (int k = 0; k < KNN; ++k) idxs[k] = mi2[k * 64 + r];

        float4 a0 = *(const float4*)(x + (size_t)q * DIM + cb + 0);
        float4 a1 = *(const float4*)(x + (size_t)q * DIM + cb + 4);
        float4 a2 = *(const float4*)(x + (size_t)q * DIM + cb + 8);
        float4 a3 = *(const float4*)(x + (size_t)q * DIM + cb + 12);

        #pragma unroll 4
        for (int k = 0; k < KNN; ++k) {
            const float* nr = x + (size_t)(bbase + idxs[k]) * DIM + cb;
            float4 v0 = *(const float4*)(nr + 0);
            float4 v1 = *(const float4*)(nr + 4);
            float4 v2 = *(const float4*)(nr + 8);
            float4 v3 = *(const float4*)(nr + 12);
            a0.x += v0.x; a0.y += v0.y; a0.z += v0.z; a0.w += v0.w;
            a1.x += v1.x; a1.y += v1.y; a1.z += v1.z; a1.w += v1.w;
            a2.x += v2.x; a2.y += v2.y; a2.z += v2.z; a2.w += v2.w;
            a3.x += v3.x; a3.y += v3.y; a3.z += v3.z; a3.w += v3.w;
        }

        float* o = agg_out + (size_t)q * DIM + cb;
        *(float4*)(o + 0)  = a0;
        *(float4*)(o + 4)  = a1;
        *(float4*)(o + 8)  = a2;
        *(float4*)(o + 12) = a3;
    }
}

// prep: transpose W1 [64][128] -> w1t [128][64] in workspace (contiguous per j)
__global__ void prep(const float* __restrict__ W1, float* __restrict__ w1t) {
    int e = blockIdx.x * 256 + threadIdx.x;   // 8192 elems
    int k = e >> 7, j = e & 127;
    w1t[j * 64 + k] = W1[e];
}

// Kernel 2: out = relu(h @ W1 + b1) @ W2 + b2, in-place on io (= d_out).
// 128 rows/block; hidden dim split across the two wave-pairs (half = tid>>7,
// wave-uniform). Weights via wave-uniform scalar loads; partial outputs
// combined through padded LDS. 512 blocks -> 2 blocks/CU -> 2 waves/SIMD.
__global__ __launch_bounds__(256, 2) void mlp(
    const float* __restrict__ w1t, const float* __restrict__ b1,
    const float* __restrict__ W2, const float* __restrict__ b2,
    float* __restrict__ io)
{
    __shared__ float hl[128 * 65];           // partial acc, stride-65 (no conflicts)

    const int tid  = threadIdx.x;
    const int r    = tid & 127;
    const int half = tid >> 7;               // wave-uniform
    const int row  = blockIdx.x * 128 + r;

    float xv[DIM];
    {
        const float4* xr = (const float4*)(io + (size_t)row * DIM);
        #pragma unroll
        for (int i = 0; i < 16; ++i) {
            float4 v = xr[i];
            xv[4*i] = v.x; xv[4*i+1] = v.y; xv[4*i+2] = v.z; xv[4*i+3] = v.w;
        }
    }

    float acc[DIM];
    #pragma unroll
    for (int c = 0; c < DIM; ++c) acc[c] = 0.0f;

    const int jb = half << 6;                // 64 hidden units per half
    #pragma unroll 2
    for (int jj = 0; jj < 64; ++jj) {
        const int j = jb + jj;
        const float* w1 = w1t + j * DIM;     // uniform row -> s_load
        float s0 = 0.f, s1 = 0.f, s2 = 0.f, s3 = 0.f;
        #pragma unroll
        for (int c = 0; c < DIM; c += 4) {
            s0 = fmaf(w1[c + 0], xv[c + 0], s0);
            s1 = fmaf(w1[c + 1], xv[c + 1], s1);
            s2 = fmaf(w1[c + 2], xv[c + 2], s2);
            s3 = fmaf(w1[c + 3], xv[c + 3], s3);
        }
        float h = fmaxf((s0 + s1) + (s2 + s3) + b1[j], 0.0f);

        const float* w2 = W2 + j * DIM;      // uniform row -> s_load
        #pragma unroll
        for (int c = 0; c < DIM; ++c)
            acc[c] = fmaf(h, w2[c], acc[c]);
    }

    if (half == 0) {
        #pragma unroll
        for (int c = 0; c < DIM; ++c) hl[r * 65 + c] = acc[c];
    }
    __syncthreads();
    if (half == 1) {
        float* o = io + (size_t)row * DIM;
        #pragma unroll
        for (int c = 0; c < DIM; c += 4) {
            float4 r4;
            r4.x = acc[c + 0] + hl[r * 65 + c + 0] + b2[c + 0];
            r4.y = acc[c + 1] + hl[r * 65 + c + 1] + b2[c + 1];
            r4.z = acc[c + 2] + hl[r * 65 + c + 2] + b2[c + 2];
            r4.w = acc[c + 3] + hl[r * 65 + c + 3] + b2[c + 3];
            *(float4*)(o + c) = r4;
        }
    }
}

extern "C" void kernel_launch(void* const* d_in, const int* in_sizes, int n_in,
                              void* d_out, int out_size, void* d_ws, size_t ws_size,
                              hipStream_t stream) {
    (void)in_sizes; (void)n_in; (void)ws_size; (void)out_size;
    const float* x   = (const float*)d_in[0];
    const float* pos = (const float*)d_in[1];
    // d_in[2] = batch indices: deterministic (i // (N/B)), not needed
    const float* W1  = (const float*)d_in[3];
    const float* b1  = (const float*)d_in[4];
    const float* W2  = (const float*)d_in[5];
    const float* b2  = (const float*)d_in[6];
    float* out = (float*)d_out;
    float* w1t = (float*)d_ws;               // 32 KB scratch

    prep<<<dim3(32), dim3(256), 0, stream>>>(W1, w1t);
    knn_agg<<<dim3(1024), dim3(256), 0, stream>>>(x, pos, out);
    mlp<<<dim3(512), dim3(256), 0, stream>>>(w1t, b1, W2, b2, out);
}

// Round 7
// 357.643 us; speedup vs baseline: 1.2846x; 1.2846x over previous
//
#include <hip/hip_runtime.h>
#include <math.h>

#define DIM  64
#define HID  128
#define KNN  16
#define SEG  1024   // candidates per wave-segment (NPB/4)
#define TSZ  128    // position tile size per segment
#define CAP  14     // per-thread LDS candidate buffer capacity

typedef unsigned long long u64;
typedef __attribute__((ext_vector_type(8))) short short8;   // 8 bf16 (4 VGPRs)
typedef __attribute__((ext_vector_type(4))) float f32x4;    // MFMA C/D
#define INF_BITS 0x7F800000u

// ---------------- bf16 helpers ----------------
__device__ __forceinline__ unsigned short bf16_rn(float f) {
    unsigned u = __float_as_uint(f);
    unsigned r = u + 0x7FFFu + ((u >> 16) & 1u);   // RN-even
    return (unsigned short)(r >> 16);
}
__device__ __forceinline__ float bf16_f32(unsigned short b) {
    return __uint_as_float(((unsigned)b) << 16);
}

// ---------------- top-16 machinery (exact, lex (d, idx)) ----------------
__device__ __forceinline__ void ins16(float (&bd)[KNN], int (&bi)[KNN],
                                      float d, int g) {
    float cd = d; int ci = g;
    #pragma unroll
    for (int i = 0; i < KNN; ++i) {
        bool lt = cd < bd[i];
        float dl = lt ? cd : bd[i];
        float dh = lt ? bd[i] : cd;
        int   il = lt ? ci : bi[i];
        int   ih = lt ? bi[i] : ci;
        bd[i] = dl; bi[i] = il; cd = dh; ci = ih;
    }
}

__device__ __forceinline__ void drain_buf(const u64* bufe, int tid,
        float (&bd)[KNN], int (&bi)[KNN], int& cnt,
        unsigned* thrU, int l) {
    for (int t = 0; t < CAP; ++t) {
        if (__ballot(t < cnt) == 0ull) break;
        u64 e = bufe[t * 256 + tid];
        float d = __uint_as_float((unsigned)e);
        int   g = (int)(e >> 32);
        if ((t < cnt) && (d < bd[KNN - 1])) ins16(bd, bi, d, g);
    }
    cnt = 0;
    atomicMin(&thrU[l], __float_as_uint(bd[KNN - 1]));
}

// float2 helpers, contraction OFF (bit-match numpy's mul/add sequence).
struct f2 { float a, b; };
__device__ __forceinline__ f2 f2mul(f2 x, float s) {
    #pragma clang fp contract(off)
    f2 r; r.a = x.a * s; r.b = x.b * s; return r;
}
__device__ __forceinline__ f2 f2add(f2 x, f2 y) {
    #pragma clang fp contract(off)
    f2 r; r.a = x.a + y.a; r.b = x.b + y.b; return r;
}
__device__ __forceinline__ f2 f2adds(f2 x, float s) {
    #pragma clang fp contract(off)
    f2 r; r.a = s + x.a; r.b = s + x.b; return r;
}
__device__ __forceinline__ f2 f2sub(f2 x, f2 y) {
    #pragma clang fp contract(off)
    f2 r; r.a = x.a - y.a; r.b = x.b - y.b; return r;
}
__device__ __forceinline__ f2 d2pair(f2 Px, f2 Py, f2 Pz, f2 Ps,
                                     float qx, float qy, float qz, float qs) {
    f2 dot = f2add(f2add(f2mul(Px, qx), f2mul(Py, qy)), f2mul(Pz, qz));
    return f2sub(f2adds(Ps, qs), f2mul(dot, 2.0f));
}

// Per-wave segment scan with cross-wave shared threshold (R5 structure,
// drain check once per 8 candidates).
template<bool CHECK>
__device__ __forceinline__ void knn_scan(
    const float* __restrict__ pos, int bbase, int segbase, int qlocal, int l,
    float qx, float qy, float qz, float qs,
    float* tx, float* ty, float* tz, float* ts,
    u64* bufe, unsigned* thrU, volatile unsigned* thrv, int tid,
    float (&bd)[KNN], int (&bi)[KNN])
{
    #pragma clang fp contract(off)
    int cnt = 0;

    #pragma unroll
    for (int m = 0; m < 2; ++m) {
        int t = (m << 6) + l;
        int g = (bbase + segbase + t) * 3;
        float ax = pos[g], ay = pos[g + 1], az = pos[g + 2];
        tx[t] = ax; ty[t] = ay; tz[t] = az;
        ts[t] = (ax * ax + ay * ay) + az * az;
    }

    __syncthreads();   // thr[] init (by wave 0) visible to all waves

    #pragma unroll
    for (int k = 0; k < KNN; ++k) { bd[k] = INFINITY; bi[k] = 0x7FFFFFFF; }
    for (int jj = 0; jj < KNN; ++jj) {
        float ax = tx[jj], ay = ty[jj], az = tz[jj], as = ts[jj];
        float dot = (ax * qx + ay * qy) + az * qz;
        float d2  = (qs + as) - 2.0f * dot;
        int cj = segbase + jj;
        if (cj == qlocal) d2 = INFINITY;
        ins16(bd, bi, d2, cj);
    }
    atomicMin(&thrU[l], __float_as_uint(bd[KNN - 1]));

    int jstart = KNN;
    for (int tb = 0; tb < SEG; tb += TSZ) {
        if (tb > 0) {
            #pragma unroll
            for (int m = 0; m < 2; ++m) {
                int t = (m << 6) + l;
                int g = (bbase + segbase + tb + t) * 3;
                float ax = pos[g], ay = pos[g + 1], az = pos[g + 2];
                tx[t] = ax; ty[t] = ay; tz[t] = az;
                ts[t] = (ax * ax + ay * ay) + az * az;
            }
        }
        for (int j = jstart; j < TSZ; j += 8) {
            float tl = __uint_as_float(thrv[l]);
            float4 X0 = *(const float4*)(tx + j);
            float4 X1 = *(const float4*)(tx + j + 4);
            float4 Y0 = *(const float4*)(ty + j);
            float4 Y1 = *(const float4*)(ty + j + 4);
            float4 Z0 = *(const float4*)(tz + j);
            float4 Z1 = *(const float4*)(tz + j + 4);
            float4 S0 = *(const float4*)(ts + j);
            float4 S1 = *(const float4*)(ts + j + 4);
            const int c0 = segbase + tb + j;

            f2 dA = d2pair({X0.x, X0.y}, {Y0.x, Y0.y}, {Z0.x, Z0.y}, {S0.x, S0.y},
                           qx, qy, qz, qs);
            f2 dB = d2pair({X0.z, X0.w}, {Y0.z, Y0.w}, {Z0.z, Z0.w}, {S0.z, S0.w},
                           qx, qy, qz, qs);
            f2 dC = d2pair({X1.x, X1.y}, {Y1.x, Y1.y}, {Z1.x, Z1.y}, {S1.x, S1.y},
                           qx, qy, qz, qs);
            f2 dD = d2pair({X1.z, X1.w}, {Y1.z, Y1.w}, {Z1.z, Z1.w}, {S1.z, S1.w},
                           qx, qy, qz, qs);
            if (CHECK) {
                int s = qlocal - c0;
                if (s == 0) dA.a = INFINITY;
                if (s == 1) dA.b = INFINITY;
                if (s == 2) dB.a = INFINITY;
                if (s == 3) dB.b = INFINITY;
                if (s == 4) dC.a = INFINITY;
                if (s == 5) dC.b = INFINITY;
                if (s == 6) dD.a = INFINITY;
                if (s == 7) dD.b = INFINITY;
            }

            if (dA.a <= tl) { bufe[cnt * 256 + tid] =
                ((u64)(unsigned)(c0 + 0) << 32) | __float_as_uint(dA.a); ++cnt; }
            if (dA.b <= tl) { bufe[cnt * 256 + tid] =
                ((u64)(unsigned)(c0 + 1) << 32) | __float_as_uint(dA.b); ++cnt; }
            if (dB.a <= tl) { bufe[cnt * 256 + tid] =
                ((u64)(unsigned)(c0 + 2) << 32) | __float_as_uint(dB.a); ++cnt; }
            if (dB.b <= tl) { bufe[cnt * 256 + tid] =
                ((u64)(unsigned)(c0 + 3) << 32) | __float_as_uint(dB.b); ++cnt; }
            if (dC.a <= tl) { bufe[cnt * 256 + tid] =
                ((u64)(unsigned)(c0 + 4) << 32) | __float_as_uint(dC.a); ++cnt; }
            if (dC.b <= tl) { bufe[cnt * 256 + tid] =
                ((u64)(unsigned)(c0 + 5) << 32) | __float_as_uint(dC.b); ++cnt; }
            if (dD.a <= tl) { bufe[cnt * 256 + tid] =
                ((u64)(unsigned)(c0 + 6) << 32) | __float_as_uint(dD.a); ++cnt; }
            if (dD.b <= tl) { bufe[cnt * 256 + tid] =
                ((u64)(unsigned)(c0 + 7) << 32) | __float_as_uint(dD.b); ++cnt; }

            if (__ballot(cnt >= CAP - 8) != 0ull)
                drain_buf(bufe, tid, bd, bi, cnt, thrU, l);
        }
        jstart = 0;
    }
    drain_buf(bufe, tid, bd, bi, cnt, thrU, l);
}

// Kernel 1: exact 16-NN + gather + aggregate. Writes h = x + sum(nb) to agg_out.
__global__ __launch_bounds__(256, 4) void knn_agg(
    const float* __restrict__ x, const float* __restrict__ pos,
    float* __restrict__ agg_out)
{
    // 36.3 KB LDS: tiles (8 KB) + thr (256 B) + u64 buffers (28 KB).
    // Phase 2 alias: md/midx (32 KB); phase 3 alias: mi2 (4 KB).
    __shared__ u64 smem[4640];

    const int tid = threadIdx.x;
    const int w   = tid >> 6;
    const int l   = tid & 63;

    const int qb     = blockIdx.x;          // 1024 blocks x 64 queries
    const int batch  = qb >> 6;
    const int bbase  = batch << 12;
    const int qlocal = ((qb & 63) << 6) + l;
    const int qglob  = bbase + qlocal;

    float* tilef = (float*)smem;            // 2048 floats
    float* tx = tilef + w * 512;
    float* ty = tx + TSZ;
    float* tz = tx + 2 * TSZ;
    float* ts = tx + 3 * TSZ;
    unsigned* thrU = (unsigned*)(tilef + 2048);       // 64 u32
    u64* bufe = smem + 1056;                          // CAP*256 u64

    if (tid < 64) thrU[tid] = INF_BITS;

    float qx, qy, qz, qs;
    {
        #pragma clang fp contract(off)
        qx = pos[3 * qglob + 0];
        qy = pos[3 * qglob + 1];
        qz = pos[3 * qglob + 2];
        qs = (qx * qx + qy * qy) + qz * qz;
    }

    float bd[KNN]; int bi[KNN];
    const int segbase = w << 10;
    const int wself   = (qb & 63) >> 4;
    if (w == wself)
        knn_scan<true >(pos, bbase, segbase, qlocal, l, qx, qy, qz, qs,
                        tx, ty, tz, ts, bufe, thrU, thrU, tid, bd, bi);
    else
        knn_scan<false>(pos, bbase, segbase, qlocal, l, qx, qy, qz, qs,
                        tx, ty, tz, ts, bufe, thrU, thrU, tid, bd, bi);

    __syncthreads();

    float* md  = (float*)smem;               // [64 slots][64 queries]
    int*  midx = (int*)(smem + 2048);
    #pragma unroll
    for (int k = 0; k < KNN; ++k) {
        int slot = (w << 4) + k;
        md[slot * 64 + l]   = bd[k];
        midx[slot * 64 + l] = bi[k];
    }
    __syncthreads();

    if (tid < 64) {
        float bd2[KNN]; int bi2[KNN];
        #pragma unroll
        for (int k = 0; k < KNN; ++k) {
            bd2[k] = md[k * 64 + tid];
            bi2[k] = midx[k * 64 + tid];
        }
        for (int c = KNN; c < 64; ++c) {
            float d = md[c * 64 + tid];
            int   g = midx[c * 64 + tid];
            if (d < bd2[KNN - 1]) ins16(bd2, bi2, d, g);
        }
        int* mi2 = (int*)smem;
        #pragma unroll
        for (int k = 0; k < KNN; ++k) mi2[k * 64 + tid] = bi2[k];
    }
    __syncthreads();

    {
        const int* mi2 = (const int*)smem;
        const int r  = tid >> 2;
        const int p  = tid & 3;
        const int q  = (qb << 6) + r;
        const int cb = p << 4;

        int idxs[KNN];
        #pragma unroll
        for (int k = 0; k < KNN; ++k) idxs[k] = mi2[k * 64 + r];

        float4 a0 = *(const float4*)(x + (size_t)q * DIM + cb + 0);
        float4 a1 = *(const float4*)(x + (size_t)q * DIM + cb + 4);
        float4 a2 = *(const float4*)(x + (size_t)q * DIM + cb + 8);
        float4 a3 = *(const float4*)(x + (size_t)q * DIM + cb + 12);

        #pragma unroll 4
        for (int k = 0; k < KNN; ++k) {
            const float* nr = x + (size_t)(bbase + idxs[k]) * DIM + cb;
            float4 v0 = *(const float4*)(nr + 0);
            float4 v1 = *(const float4*)(nr + 4);
            float4 v2 = *(const float4*)(nr + 8);
            float4 v3 = *(const float4*)(nr + 12);
            a0.x += v0.x; a0.y += v0.y; a0.z += v0.z; a0.w += v0.w;
            a1.x += v1.x; a1.y += v1.y; a1.z += v1.z; a1.w += v1.w;
            a2.x += v2.x; a2.y += v2.y; a2.z += v2.z; a2.w += v2.w;
            a3.x += v3.x; a3.y += v3.y; a3.z += v3.z; a3.w += v3.w;
        }

        float* o = agg_out + (size_t)q * DIM + cb;
        *(float4*)(o + 0)  = a0;
        *(float4*)(o + 4)  = a1;
        *(float4*)(o + 8)  = a2;
        *(float4*)(o + 12) = a3;
    }
}

// ============ MFMA MLP path ============
// ws layout (ushort elems): w1h[128][64] @0, w1l @8192, w2h[64][128] @16384,
// w2l @24576.  (W stored transposed: [n][k], k contiguous = B-frag friendly.)
__global__ void prep_bf16(const float* __restrict__ W1,
                          const float* __restrict__ W2,
                          unsigned short* __restrict__ ws) {
    int e = blockIdx.x * 256 + threadIdx.x;   // 16384 threads
    if (e < 8192) {
        int n = e >> 6, k = e & 63;
        float v = W1[k * HID + n];
        unsigned short h = bf16_rn(v);
        ws[e] = h;
        ws[8192 + e] = bf16_rn(v - bf16_f32(h));
    } else {
        int f = e - 8192;
        int n = f >> 7, k = f & 127;
        float v = W2[k * DIM + n];
        unsigned short h = bf16_rn(v);
        ws[16384 + f] = h;
        ws[24576 + f] = bf16_rn(v - bf16_f32(h));
    }
}

// out = relu(h @ W1 + b1) @ W2 + b2, in-place on io. 64 rows/block, 16/wave.
// bf16 MFMA, 3-term split (Ah*Bh + Ah*Bl + Al*Bh) ~= fp32 precision.
// Frag layouts (learn_hip m89/m120): A[m=lane&15][k=quad*8+j],
// B[k=quad*8+j][n=lane&15], C/D[row=quad*4+reg][col=lane&15].
__global__ __launch_bounds__(256, 2) void mlp_mfma(
    const unsigned short* __restrict__ ws,
    const float* __restrict__ b1, const float* __restrict__ b2,
    float* __restrict__ io)
{
    __shared__ unsigned short hh[64 * 136];   // h split-hi, padded stride
    __shared__ unsigned short hl[64 * 136];   // h split-lo

    const int tid  = threadIdx.x;
    const int w    = tid >> 6;
    const int lane = tid & 63;
    const int quad = lane >> 4;
    const int col  = lane & 15;
    const int rowbase = blockIdx.x * 64 + w * 16;

    const unsigned short* w1h = ws;
    const unsigned short* w1l = ws + 8192;
    const unsigned short* w2h = ws + 16384;
    const unsigned short* w2l = ws + 24576;

    // ---- A-frags for GEMM1: x rows (fp32 -> bf16 hi/lo in-register) ----
    short8 ah[2], al[2];
    #pragma unroll
    for (int ks = 0; ks < 2; ++ks) {
        const float* xr = io + (size_t)(rowbase + col) * DIM + ks * 32 + quad * 8;
        float4 v0 = *(const float4*)(xr);
        float4 v1 = *(const float4*)(xr + 4);
        float xv[8] = {v0.x, v0.y, v0.z, v0.w, v1.x, v1.y, v1.z, v1.w};
        #pragma unroll
        for (int j = 0; j < 8; ++j) {
            unsigned short hb = bf16_rn(xv[j]);
            ah[ks][j] = (short)hb;
            al[ks][j] = (short)bf16_rn(xv[j] - bf16_f32(hb));
        }
    }

    // ---- GEMM1: h[16 x 128] = x[16 x 64] @ W1[64 x 128] ----
    f32x4 acc1[8];
    #pragma unroll
    for (int t = 0; t < 8; ++t) acc1[t] = (f32x4){0.f, 0.f, 0.f, 0.f};

    #pragma unroll
    for (int t = 0; t < 8; ++t) {
        #pragma unroll
        for (int ks = 0; ks < 2; ++ks) {
            const int off = (t * 16 + col) * 64 + ks * 32 + quad * 8;
            short8 bh = *(const short8*)(w1h + off);
            short8 bl = *(const short8*)(w1l + off);
            acc1[t] = __builtin_amdgcn_mfma_f32_16x16x32_bf16(ah[ks], bh, acc1[t], 0, 0, 0);
            acc1[t] = __builtin_amdgcn_mfma_f32_16x16x32_bf16(al[ks], bh, acc1[t], 0, 0, 0);
            acc1[t] = __builtin_amdgcn_mfma_f32_16x16x32_bf16(ah[ks], bl, acc1[t], 0, 0, 0);
        }
    }

    // ---- epilogue 1: bias + relu, split to bf16, stage to LDS ----
    #pragma unroll
    for (int t = 0; t < 8; ++t) {
        float bv = b1[t * 16 + col];
        #pragma unroll
        for (int r = 0; r < 4; ++r) {
            float h = fmaxf(acc1[t][r] + bv, 0.0f);
            unsigned short hb = bf16_rn(h);
            unsigned short lb = bf16_rn(h - bf16_f32(hb));
            int rowL = w * 16 + quad * 4 + r;
            hh[rowL * 136 + t * 16 + col] = hb;
            hl[rowL * 136 + t * 16 + col] = lb;
        }
    }
    __syncthreads();

    // ---- GEMM2: out[16 x 64] = h[16 x 128] @ W2[128 x 64] ----
    short8 a2h[4], a2l[4];
    #pragma unroll
    for (int ks = 0; ks < 4; ++ks) {
        const int off = (w * 16 + col) * 136 + ks * 32 + quad * 8;
        a2h[ks] = *(const short8*)(hh + off);
        a2l[ks] = *(const short8*)(hl + off);
    }

    f32x4 acc2[4];
    #pragma unroll
    for (int t = 0; t < 4; ++t) acc2[t] = (f32x4){0.f, 0.f, 0.f, 0.f};

    #pragma unroll
    for (int t = 0; t < 4; ++t) {
        #pragma unroll
        for (int ks = 0; ks < 4; ++ks) {
            const int off = (t * 16 + col) * 128 + ks * 32 + quad * 8;
            short8 bh = *(const short8*)(w2h + off);
            short8 bl = *(const short8*)(w2l + off);
            acc2[t] = __builtin_amdgcn_mfma_f32_16x16x32_bf16(a2h[ks], bh, acc2[t], 0, 0, 0);
            acc2[t] = __builtin_amdgcn_mfma_f32_16x16x32_bf16(a2l[ks], bh, acc2[t], 0, 0, 0);
            acc2[t] = __builtin_amdgcn_mfma_f32_16x16x32_bf16(a2h[ks], bl, acc2[t], 0, 0, 0);
        }
    }

    // ---- epilogue 2: bias + store (in-place; own wave's rows only) ----
    #pragma unroll
    for (int t = 0; t < 4; ++t) {
        float bv = b2[t * 16 + col];
        #pragma unroll
        for (int r = 0; r < 4; ++r) {
            io[(size_t)(rowbase + quad * 4 + r) * DIM + t * 16 + col] =
                acc2[t][r] + bv;
        }
    }
}

// ============ VALU fallback (only if workspace < 64 KB) ============
__global__ void prep_f32(const float* __restrict__ W1, float* __restrict__ w1t) {
    int e = blockIdx.x * 256 + threadIdx.x;
    int k = e >> 7, j = e & 127;
    w1t[j * 64 + k] = W1[e];
}

__global__ __launch_bounds__(256, 2) void mlp_valu(
    const float* __restrict__ w1t, const float* __restrict__ b1,
    const float* __restrict__ W2, const float* __restrict__ b2,
    float* __restrict__ io)
{
    __shared__ float hlds[128 * 65];
    const int tid  = threadIdx.x;
    const int r    = tid & 127;
    const int half = tid >> 7;
    const int row  = blockIdx.x * 128 + r;

    float xv[DIM];
    {
        const float4* xr = (const float4*)(io + (size_t)row * DIM);
        #pragma unroll
        for (int i = 0; i < 16; ++i) {
            float4 v = xr[i];
            xv[4*i] = v.x; xv[4*i+1] = v.y; xv[4*i+2] = v.z; xv[4*i+3] = v.w;
        }
    }
    float acc[DIM];
    #pragma unroll
    for (int c = 0; c < DIM; ++c) acc[c] = 0.0f;

    const int jb = half << 6;
    for (int jj = 0; jj < 64; ++jj) {
        const int j = jb + jj;
        const float* w1 = w1t + j * DIM;
        float s0 = 0.f, s1 = 0.f, s2 = 0.f, s3 = 0.f;
        #pragma unroll
        for (int c = 0; c < DIM; c += 4) {
            s0 = fmaf(w1[c + 0], xv[c + 0], s0);
            s1 = fmaf(w1[c + 1], xv[c + 1], s1);
            s2 = fmaf(w1[c + 2], xv[c + 2], s2);
            s3 = fmaf(w1[c + 3], xv[c + 3], s3);
        }
        float h = fmaxf((s0 + s1) + (s2 + s3) + b1[j], 0.0f);
        const float* w2 = W2 + j * DIM;
        #pragma unroll
        for (int c = 0; c < DIM; ++c) acc[c] = fmaf(h, w2[c], acc[c]);
    }

    if (half == 0) {
        #pragma unroll
        for (int c = 0; c < DIM; ++c) hlds[r * 65 + c] = acc[c];
    }
    __syncthreads();
    if (half == 1) {
        float* o = io + (size_t)row * DIM;
        #pragma unroll
        for (int c = 0; c < DIM; c += 4) {
            float4 r4;
            r4.x = acc[c + 0] + hlds[r * 65 + c + 0] + b2[c + 0];
            r4.y = acc[c + 1] + hlds[r * 65 + c + 1] + b2[c + 1];
            r4.z = acc[c + 2] + hlds[r * 65 + c + 2] + b2[c + 2];
            r4.w = acc[c + 3] + hlds[r * 65 + c + 3] + b2[c + 3];
            *(float4*)(o + c) = r4;
        }
    }
}

extern "C" void kernel_launch(void* const* d_in, const int* in_sizes, int n_in,
                              void* d_out, int out_size, void* d_ws, size_t ws_size,
                              hipStream_t stream) {
    (void)in_sizes; (void)n_in; (void)out_size;
    const float* x   = (const float*)d_in[0];
    const float* pos = (const float*)d_in[1];
    // d_in[2] = batch indices: deterministic (i // (N/B)), not needed
    const float* W1  = (const float*)d_in[3];
    const float* b1  = (const float*)d_in[4];
    const float* W2  = (const float*)d_in[5];
    const float* b2  = (const float*)d_in[6];
    float* out = (float*)d_out;

    if (ws_size >= 65536) {
        prep_bf16<<<dim3(64), dim3(256), 0, stream>>>(W1, W2, (unsigned short*)d_ws);
        knn_agg<<<dim3(1024), dim3(256), 0, stream>>>(x, pos, out);
        mlp_mfma<<<dim3(1024), dim3(256), 0, stream>>>(
            (const unsigned short*)d_ws, b1, b2, out);
    } else {
        prep_f32<<<dim3(32), dim3(256), 0, stream>>>(W1, (float*)d_ws);
        knn_agg<<<dim3(1024), dim3(256), 0, stream>>>(x, pos, out);
        mlp_valu<<<dim3(512), dim3(256), 0, stream>>>(
            (const float*)d_ws, b1, W2, b2, out);
    }
}